// Round 9
// baseline (159.684 us; speedup 1.0000x reference)
//
#include <hip/hip_runtime.h>
#include <stdint.h>

#define Bn 4
#define Tn 2048
#define Cn 1024
#define Hn 16
#define HSn 64
#define Mn (Bn*Tn)
#define N1n (3*Cn)

typedef unsigned short u16;
typedef unsigned int u32;
typedef __attribute__((ext_vector_type(8))) short short8;
typedef __attribute__((ext_vector_type(4))) float f32x4;
typedef __attribute__((ext_vector_type(16))) float f32x16;

#define QSCf (0.125f * 1.44269504f)

__device__ __forceinline__ u16 f2bf(float f){
  u32 u = __float_as_uint(f);
  u += 0x7fffu + ((u >> 16) & 1u);
  return (u16)(u >> 16);
}

__device__ __forceinline__ u32 pkbf(float lo, float hi_){
  u32 r; asm("v_cvt_pk_bf16_f32 %0, %1, %2" : "=v"(r) : "v"(lo), "v"(hi_)); return r;
}

__device__ __forceinline__ float fexp2(float x){
  float r; asm("v_exp_f32 %0, %1" : "=v"(r) : "v"(x)); return r;
}

__device__ __forceinline__ float fmax3(float a, float b, float c){
  float r; asm("v_max3_f32 %0, %1, %2, %3" : "=v"(r) : "v"(a), "v"(b), "v"(c)); return r;
}

__device__ __forceinline__ void plswap(u32 &a, u32 &b){
  auto r = __builtin_amdgcn_permlane32_swap(a, b, false, false);
  a = r[0]; b = r[1];
}

__device__ __forceinline__ void gload_lds16(const void* g, void* l){
  __builtin_amdgcn_global_load_lds(
      (const __attribute__((address_space(1))) u32*)g,
      (__attribute__((address_space(3))) u32*)l, 16, 0, 0);
}

#define BARRIER() __builtin_amdgcn_s_barrier()
#define CFENCE() asm volatile("" ::: "memory")

// ---- fused pre-pass: x->bf16 | w_attn^T->bf16 | w_proj^T->bf16 ----
__device__ __forceinline__ void tcvt_body(const float* __restrict__ in,
                                          u16* __restrict__ out,
                                          int R, int Cc, int bxx, int byy,
                                          float sh[64][68]){
  int tid = threadIdx.x;
  int c0 = bxx*64, r0 = byy*64;
  int rr = tid >> 4, c4 = (tid & 15) * 4;
  #pragma unroll
  for (int p=0;p<4;p++){
    int r = rr + 16*p;
    *(float4*)&sh[r][c4] = *(const float4*)&in[(size_t)(r0+r)*Cc + c0 + c4];
  }
  __syncthreads();
  #pragma unroll
  for (int p=0;p<4;p++){
    int oc = rr + 16*p;
    u32 w0 = (u32)f2bf(sh[c4+0][oc]) | ((u32)f2bf(sh[c4+1][oc]) << 16);
    u32 w1 = (u32)f2bf(sh[c4+2][oc]) | ((u32)f2bf(sh[c4+3][oc]) << 16);
    uint2 pk; pk.x = w0; pk.y = w1;
    *(uint2*)&out[(size_t)(c0+oc)*R + r0 + c4] = pk;
  }
}

__global__ __launch_bounds__(256)
void k_pre(const float* __restrict__ x, const float* __restrict__ wa,
           const float* __restrict__ wp, u16* __restrict__ xb,
           u16* __restrict__ waT, u16* __restrict__ wpT){
  __shared__ float sh[64][68];
  int bid = blockIdx.x;
  if (bid < 4096){
    int i = bid*256 + threadIdx.x;
    const float4* p = (const float4*)(x) + (size_t)i*2;
    float4 a = p[0], b = p[1];
    uint4 r;
    r.x = (u32)f2bf(a.x) | ((u32)f2bf(a.y) << 16);
    r.y = (u32)f2bf(a.z) | ((u32)f2bf(a.w) << 16);
    r.z = (u32)f2bf(b.x) | ((u32)f2bf(b.y) << 16);
    r.w = (u32)f2bf(b.z) | ((u32)f2bf(b.w) << 16);
    *((uint4*)(xb) + i) = r;
  } else if (bid < 4096 + 768){
    int b2 = bid - 4096;
    tcvt_body(wa, waT, Cn, N1n, b2 % 48, b2 / 48, sh);
  } else {
    int b3 = bid - 4864;
    tcvt_body(wp, wpT, Cn, Cn, b3 % 16, b3 / 16, sh);
  }
}

// ---- 128x128 counted-vmcnt GEMM: C = A . Bt^T + bias ----
template <int MODE>
__global__ __launch_bounds__(256, 2)
void k_gemm2(const u16* __restrict__ A, const u16* __restrict__ Bt,
             const float* __restrict__ bias, void* __restrict__ Cout,
             u16* __restrict__ vt, int Nn_, int byPerXcd)
{
  extern __shared__ char smem[];
  const int nkt = 16;
  int tid = threadIdx.x;
  int wave = tid >> 6, lane = tid & 63, g = lane >> 4, cl = lane & 15;
  int wm = wave >> 1, wn = wave & 1;

  int xcd = blockIdx.x & 7, idx = blockIdx.x >> 3;
  int by = xcd * byPerXcd + (idx % byPerXcd);
  int bx = idx / byPerXcd;
  int m0 = by * 128, n0 = bx * 128;

  int srow = tid >> 3;
  int scolb = (tid & 7) << 4;
  int ssw = scolb ^ ((srow & 7) << 4);
  const char* Agp = (const char*)A  + (size_t)(m0 + srow) * 2048 + ssw;
  const char* Bgp = (const char*)Bt + (size_t)(n0 + srow) * 2048 + ssw;

  #define STG(t_, b_) { \
    const char* ag = Agp + (size_t)(t_)*128; \
    const char* bg = Bgp + (size_t)(t_)*128; \
    char* ab = smem + (b_)*32768 + (wave<<10); \
    char* bb = ab + 16384; \
    gload_lds16(ag,          ab); \
    gload_lds16(ag+ 65536,   ab+4096); \
    gload_lds16(ag+131072,   ab+8192); \
    gload_lds16(ag+196608,   ab+12288); \
    gload_lds16(bg,          bb); \
    gload_lds16(bg+ 65536,   bb+4096); \
    gload_lds16(bg+131072,   bb+8192); \
    gload_lds16(bg+196608,   bb+12288); }

  f32x4 acc[4][4];
  #pragma unroll
  for (int i=0;i<4;i++)
    #pragma unroll
    for (int j=0;j<4;j++) acc[i][j] = (f32x4){0.f,0.f,0.f,0.f};

  STG(0, 0);

  for (int t=0; t<nkt; ++t){
    int b = t & 1;
    if (t+1 < nkt){
      STG(t+1, b^1);
      asm volatile("s_waitcnt vmcnt(8)" ::: "memory");
    } else {
      asm volatile("s_waitcnt vmcnt(0)" ::: "memory");
    }
    BARRIER(); CFENCE();
    const char* Asb = smem + b*32768;
    const char* Bsb = Asb + 16384;
    short8 a[4][2], bq[4][2];
    #pragma unroll
    for (int i=0;i<4;i++){
      int row = wm*64 + i*16 + cl;
      #pragma unroll
      for (int ks=0;ks<2;ks++)
        a[i][ks] = *(const short8*)(Asb + row*128 + ((ks*64 + g*16) ^ ((row&7)<<4)));
    }
    #pragma unroll
    for (int j=0;j<4;j++){
      int row = wn*64 + j*16 + cl;
      #pragma unroll
      for (int ks=0;ks<2;ks++)
        bq[j][ks] = *(const short8*)(Bsb + row*128 + ((ks*64 + g*16) ^ ((row&7)<<4)));
    }
    asm volatile("s_waitcnt lgkmcnt(0)" ::: "memory");
    __builtin_amdgcn_s_setprio(1);
    #pragma unroll
    for (int ks=0;ks<2;ks++)
      #pragma unroll
      for (int i=0;i<4;i++)
        #pragma unroll
        for (int j=0;j<4;j++)
          acc[i][j] = __builtin_amdgcn_mfma_f32_16x16x32_bf16(a[i][ks], bq[j][ks], acc[i][j], 0, 0, 0);
    __builtin_amdgcn_s_setprio(0);
    CFENCE(); BARRIER(); CFENCE();
  }
  #undef STG

  #pragma unroll
  for (int jj=0;jj<4;jj++){
    int col = n0 + wn*64 + jj*16 + cl;
    float bj = bias[col];
    if (MODE == 0){
      #pragma unroll
      for (int i=0;i<4;i++){
        int rowb = m0 + wm*64 + i*16 + g*4;
        #pragma unroll
        for (int r=0;r<4;r++)
          ((float*)Cout)[(size_t)(rowb+r)*Nn_ + col] = acc[i][jj][r] + bj;
      }
    } else if (col < 2*Cn){
      float sc = (col < Cn) ? QSCf : 1.0f;
      #pragma unroll
      for (int i=0;i<4;i++){
        int rowb = m0 + wm*64 + i*16 + g*4;
        #pragma unroll
        for (int r=0;r<4;r++)
          ((u16*)Cout)[(size_t)(rowb+r)*Nn_ + col] = f2bf((acc[i][jj][r] + bj) * sc);
      }
    } else {
      int hd = col - 2*Cn;
      #pragma unroll
      for (int i=0;i<4;i++){
        int rowb = m0 + wm*64 + i*16 + g*4;
        int bb = rowb >> 11, tt = rowb & 2047;
        u16* dst = vt + (((size_t)(bb*16 + (hd>>6)))*64 + (hd&63))*2048 + tt;
        uint2 pk;
        pk.x = (u32)f2bf(acc[i][jj][0]+bj) | ((u32)f2bf(acc[i][jj][1]+bj) << 16);
        pk.y = (u32)f2bf(acc[i][jj][2]+bj) | ((u32)f2bf(acc[i][jj][3]+bj) << 16);
        *(uint2*)dst = pk;
      }
    }
  }
}

// ------- causal flash attention: dual-stream 32x32 swapped-QK^T -------
// grid 512: blk -> (xcd, bh, sel); qt = sel<4 ? 7-sel : sel-4 (CU pairs sum 36).
// Block = 256 q-rows; each wave runs TWO independent 32-row streams (A,B)
// over shared K/V LDS tiles: kf/vf loaded once, feed both streams' MFMAs.
__global__ __launch_bounds__(256, 2)
void k_attn(const u16* __restrict__ qkv, const u16* __restrict__ vt, u16* __restrict__ yb){
  __shared__ __align__(16) u16 Ks[2][64*64];
  __shared__ __align__(16) u16 Vs[2][64*64];
  int tid = threadIdx.x, wave = tid >> 6, lane = tid & 63;
  int ql = lane & 31, hi = lane >> 5;
  int blk = blockIdx.x;
  int xcd = blk & 7, rest = blk >> 3;
  int bh  = xcd + 8*(rest & 7);
  int sel = rest >> 3;                    // 0..7
  int qt  = (sel < 4) ? (7 - sel) : (sel - 4);
  int b = bh >> 4, h = bh & 15;

  const u16* Kbase = qkv + (size_t)b*Tn*N1n + Cn + h*HSn;
  const u16* Vbase = vt  + (size_t)bh*HSn*Tn;

  auto STAGE = [&](int bufi, int kt){
    int kb_ = kt*64;
    #pragma unroll
    for (int it=0; it<2; ++it){
      int off = it*4096 + tid*16;
      int row = off >> 7;
      int cb  = off & 127;
      int gc  = (cb ^ ((row & 7) << 4)) >> 1;
      gload_lds16(Kbase + (size_t)(kb_ + row)*N1n + gc,
                  (char*)&Ks[bufi][0] + it*4096 + (wave << 10));
      gload_lds16(Vbase + (size_t)row*Tn + kb_ + gc,
                  (char*)&Vs[bufi][0] + it*4096 + (wave << 10));
    }
  };

  int q0 = qt * 256;
  int qw0A = q0 + wave*64;
  int qw0B = qw0A + 32;
  int qgA = qw0A + ql, qgB = qw0B + ql;
  int ntiles = 4*qt + 4;

  const u16* QpA = qkv + (size_t)(b*Tn + qgA)*N1n + h*HSn;
  const u16* QpB = qkv + (size_t)(b*Tn + qgB)*N1n + h*HSn;
  short8 qfA[4], qfB[4];
  #pragma unroll
  for (int dc=0; dc<4; ++dc){
    qfA[dc] = *(const short8*)&QpA[dc*16 + hi*8];
    qfB[dc] = *(const short8*)&QpB[dc*16 + hi*8];
  }

  f32x16 oA0, oA1, oB0, oB1;
  #pragma unroll
  for (int r=0; r<16; ++r){ oA0[r]=0.f; oA1[r]=0.f; oB0[r]=0.f; oB1[r]=0.f; }
  float mA = -1e30f, lA = 0.f, mB = -1e30f, lB = 0.f;

  auto SMPV = [&](f32x16& s, int qg_, int qw0_, float& m_, float& l_,
                  f32x16& o0, f32x16& o1, int kbase,
                  short8 vf00, short8 vf01, short8 vf10, short8 vf11){
    float p[16];
    if (kbase + 31 > qw0_){
      #pragma unroll
      for (int r=0; r<16; ++r){
        int krow = kbase + (r&3) + 8*(r>>2) + 4*hi;
        p[r] = (krow > qg_) ? -1e30f : s[r];
      }
    } else {
      #pragma unroll
      for (int r=0; r<16; ++r) p[r] = s[r];
    }
    float r0 = fmax3(p[0], p[1], p[2]);
    float r1 = fmax3(p[3], p[4], p[5]);
    float r2 = fmax3(p[6], p[7], p[8]);
    float r3 = fmax3(p[9], p[10], p[11]);
    float r4 = fmax3(p[12], p[13], p[14]);
    float tm = fmaxf(fmax3(r0, r1, r2), fmax3(r3, r4, p[15]));
    { u32 ua = __float_as_uint(tm), ub = ua; plswap(ua, ub);
      tm = fmaxf(__uint_as_float(ua), __uint_as_float(ub)); }
    if (!__all(tm - m_ <= 8.0f)){
      float mn = fmaxf(m_, tm);
      float al = fexp2(m_ - mn);
      m_ = mn; l_ *= al;
      #pragma unroll
      for (int r=0; r<16; ++r){ o0[r] *= al; o1[r] *= al; }
    }
    float ls = 0.f;
    #pragma unroll
    for (int r=0; r<16; ++r){ float e = fexp2(p[r] - m_); p[r] = e; ls += e; }
    { u32 ua = __float_as_uint(ls), ub = ua; plswap(ua, ub);
      l_ += __uint_as_float(ua) + __uint_as_float(ub); }
    #pragma unroll
    for (int ks=0; ks<2; ++ks){
      int pb = ks*8;
      u32 w0 = pkbf(p[pb+0], p[pb+1]);
      u32 w1 = pkbf(p[pb+2], p[pb+3]);
      u32 w2 = pkbf(p[pb+4], p[pb+5]);
      u32 w3 = pkbf(p[pb+6], p[pb+7]);
      plswap(w0, w2);
      plswap(w1, w3);
      union { u32 w[4]; short8 v; } pu;
      pu.w[0] = w0; pu.w[1] = w1; pu.w[2] = w2; pu.w[3] = w3;
      __builtin_amdgcn_s_setprio(1);
      o0 = __builtin_amdgcn_mfma_f32_32x32x16_bf16(ks ? vf10 : vf00, pu.v, o0, 0, 0, 0);
      o1 = __builtin_amdgcn_mfma_f32_32x32x16_bf16(ks ? vf11 : vf01, pu.v, o1, 0, 0, 0);
      __builtin_amdgcn_s_setprio(0);
    }
  };

  STAGE(0, 0);
  asm volatile("s_waitcnt vmcnt(0)" ::: "memory");
  __syncthreads();
  int buf = 0;

  for (int kt=0; kt<ntiles; ++kt){
    if (kt+1 < ntiles) STAGE(buf^1, kt+1);
    const char* Ksb = (const char*)&Ks[buf][0];
    const char* Vsb = (const char*)&Vs[buf][0];
    #pragma unroll
    for (int ksub=0; ksub<2; ++ksub){
      int kbase = kt*64 + ksub*32;
      if (kbase <= qw0B + 31){
        bool actA = (kbase <= qw0A + 31);
        int krow7 = ((ksub*32 + ql) << 7);
        int xsw = ((ql & 7) << 4);
        short8 kf0 = *(const short8*)(Ksb + krow7 + ((  0 + hi*16) ^ xsw));
        short8 kf1 = *(const short8*)(Ksb + krow7 + (( 32 + hi*16) ^ xsw));
        short8 kf2 = *(const short8*)(Ksb + krow7 + (( 64 + hi*16) ^ xsw));
        short8 kf3 = *(const short8*)(Ksb + krow7 + (( 96 + hi*16) ^ xsw));
        short8 vf00 = *(const short8*)(Vsb + ((     ql) << 7) + ((ksub*64 +  0 + hi*16) ^ xsw));
        short8 vf01 = *(const short8*)(Vsb + ((32 + ql) << 7) + ((ksub*64 +  0 + hi*16) ^ xsw));
        short8 vf10 = *(const short8*)(Vsb + ((     ql) << 7) + ((ksub*64 + 32 + hi*16) ^ xsw));
        short8 vf11 = *(const short8*)(Vsb + ((32 + ql) << 7) + ((ksub*64 + 32 + hi*16) ^ xsw));
        f32x16 sA, sB;
        #pragma unroll
        for (int r=0; r<16; ++r){ sA[r]=0.f; sB[r]=0.f; }
        __builtin_amdgcn_s_setprio(1);
        if (actA){
          sA = __builtin_amdgcn_mfma_f32_32x32x16_bf16(kf0, qfA[0], sA, 0, 0, 0);
          sA = __builtin_amdgcn_mfma_f32_32x32x16_bf16(kf1, qfA[1], sA, 0, 0, 0);
          sA = __builtin_amdgcn_mfma_f32_32x32x16_bf16(kf2, qfA[2], sA, 0, 0, 0);
          sA = __builtin_amdgcn_mfma_f32_32x32x16_bf16(kf3, qfA[3], sA, 0, 0, 0);
        }
        sB = __builtin_amdgcn_mfma_f32_32x32x16_bf16(kf0, qfB[0], sB, 0, 0, 0);
        sB = __builtin_amdgcn_mfma_f32_32x32x16_bf16(kf1, qfB[1], sB, 0, 0, 0);
        sB = __builtin_amdgcn_mfma_f32_32x32x16_bf16(kf2, qfB[2], sB, 0, 0, 0);
        sB = __builtin_amdgcn_mfma_f32_32x32x16_bf16(kf3, qfB[3], sB, 0, 0, 0);
        __builtin_amdgcn_s_setprio(0);
        if (actA) SMPV(sA, qgA, qw0A, mA, lA, oA0, oA1, kbase, vf00, vf01, vf10, vf11);
        SMPV(sB, qgB, qw0B, mB, lB, oB0, oB1, kbase, vf00, vf01, vf10, vf11);
      }
    }
    asm volatile("s_waitcnt vmcnt(0)" ::: "memory");
    __syncthreads();
    buf ^= 1;
  }

  {
    float rl = 1.0f / lA;
    u16* yp = yb + (size_t)(b*Tn + qgA)*Cn + h*HSn;
    #pragma unroll
    for (int rq=0; rq<4; ++rq){
      int d0 = rq*8 + hi*4;
      uint2 pk2;
      pk2.x = (u32)f2bf(oA0[rq*4+0]*rl) | ((u32)f2bf(oA0[rq*4+1]*rl) << 16);
      pk2.y = (u32)f2bf(oA0[rq*4+2]*rl) | ((u32)f2bf(oA0[rq*4+3]*rl) << 16);
      *(uint2*)&yp[d0] = pk2;
      pk2.x = (u32)f2bf(oA1[rq*4+0]*rl) | ((u32)f2bf(oA1[rq*4+1]*rl) << 16);
      pk2.y = (u32)f2bf(oA1[rq*4+2]*rl) | ((u32)f2bf(oA1[rq*4+3]*rl) << 16);
      *(uint2*)&yp[32 + d0] = pk2;
    }
  }
  {
    float rl = 1.0f / lB;
    u16* yp = yb + (size_t)(b*Tn + qgB)*Cn + h*HSn;
    #pragma unroll
    for (int rq=0; rq<4; ++rq){
      int d0 = rq*8 + hi*4;
      uint2 pk2;
      pk2.x = (u32)f2bf(oB0[rq*4+0]*rl) | ((u32)f2bf(oB0[rq*4+1]*rl) << 16);
      pk2.y = (u32)f2bf(oB0[rq*4+2]*rl) | ((u32)f2bf(oB0[rq*4+3]*rl) << 16);
      *(uint2*)&yp[d0] = pk2;
      pk2.x = (u32)f2bf(oB1[rq*4+0]*rl) | ((u32)f2bf(oB1[rq*4+1]*rl) << 16);
      pk2.y = (u32)f2bf(oB1[rq*4+2]*rl) | ((u32)f2bf(oB1[rq*4+3]*rl) << 16);
      *(uint2*)&yp[32 + d0] = pk2;
    }
  }
}

extern "C" void kernel_launch(void* const* d_in, const int* in_sizes, int n_in,
                              void* d_out, int out_size, void* d_ws, size_t ws_size,
                              hipStream_t stream)
{
  const float* x      = (const float*)d_in[0];
  const float* w_attn = (const float*)d_in[1];
  const float* b_attn = (const float*)d_in[2];
  const float* w_proj = (const float*)d_in[3];
  const float* b_proj = (const float*)d_in[4];
  float* out = (float*)d_out;
  char* ws = (char*)d_ws;

  size_t off = 0;
  u16* xb  = (u16*)(ws + off); off += (size_t)Mn*Cn*2;
  u16* waT = (u16*)(ws + off); off += (size_t)N1n*Cn*2;
  u16* wpT = (u16*)(ws + off); off += (size_t)Cn*Cn*2;
  u16* qkv = (u16*)(ws + off); off += (size_t)Mn*N1n*2;
  u16* vt  = (u16*)(ws + off); off += (size_t)Bn*Hn*HSn*Tn*2;
  u16* yb  = (u16*)(ws + off); off += (size_t)Mn*Cn*2;

  (void)hipFuncSetAttribute((const void*)k_gemm2<1>,
        hipFuncAttributeMaxDynamicSharedMemorySize, 65536);
  (void)hipFuncSetAttribute((const void*)k_gemm2<0>,
        hipFuncAttributeMaxDynamicSharedMemorySize, 65536);

  k_pre<<<dim3(5120), 256, 0, stream>>>(x, w_attn, w_proj, xb, waT, wpT);
  k_gemm2<1><<<dim3((Mn/128)*(N1n/128)), 256, 65536, stream>>>(xb, waT, b_attn, qkv, vt, N1n, 8);
  k_attn<<<dim3(512), 256, 0, stream>>>(qkv, vt, yb);
  k_gemm2<0><<<dim3((Mn/128)*(Cn/128)), 256, 65536, stream>>>(yb, wpT, b_proj, out, nullptr, Cn, 8);
}

// Round 10
// 154.089 us; speedup vs baseline: 1.0363x; 1.0363x over previous
//
#include <hip/hip_runtime.h>
#include <stdint.h>

#define Bn 4
#define Tn 2048
#define Cn 1024
#define Hn 16
#define HSn 64
#define Mn (Bn*Tn)
#define N1n (3*Cn)

typedef unsigned short u16;
typedef unsigned int u32;
typedef __attribute__((ext_vector_type(8))) short short8;
typedef __attribute__((ext_vector_type(4))) float f32x4;
typedef __attribute__((ext_vector_type(16))) float f32x16;

#define QSCf (0.125f * 1.44269504f)

__device__ __forceinline__ u16 f2bf(float f){
  u32 u = __float_as_uint(f);
  u += 0x7fffu + ((u >> 16) & 1u);
  return (u16)(u >> 16);
}

__device__ __forceinline__ u32 pkbf(float lo, float hi_){
  u32 r; asm("v_cvt_pk_bf16_f32 %0, %1, %2" : "=v"(r) : "v"(lo), "v"(hi_)); return r;
}

__device__ __forceinline__ float fexp2(float x){
  float r; asm("v_exp_f32 %0, %1" : "=v"(r) : "v"(x)); return r;
}

__device__ __forceinline__ float fmax3(float a, float b, float c){
  float r; asm("v_max3_f32 %0, %1, %2, %3" : "=v"(r) : "v"(a), "v"(b), "v"(c)); return r;
}

__device__ __forceinline__ void plswap(u32 &a, u32 &b){
  auto r = __builtin_amdgcn_permlane32_swap(a, b, false, false);
  a = r[0]; b = r[1];
}

__device__ __forceinline__ void gload_lds16(const void* g, void* l){
  __builtin_amdgcn_global_load_lds(
      (const __attribute__((address_space(1))) u32*)g,
      (__attribute__((address_space(3))) u32*)l, 16, 0, 0);
}

#define BARRIER() __builtin_amdgcn_s_barrier()
#define CFENCE() asm volatile("" ::: "memory")

// ---- fused pre-pass: x->bf16 | w_attn^T->bf16 | w_proj^T->bf16 ----
__device__ __forceinline__ void tcvt_body(const float* __restrict__ in,
                                          u16* __restrict__ out,
                                          int R, int Cc, int bxx, int byy,
                                          float sh[64][68]){
  int tid = threadIdx.x;
  int c0 = bxx*64, r0 = byy*64;
  int rr = tid >> 4, c4 = (tid & 15) * 4;
  #pragma unroll
  for (int p=0;p<4;p++){
    int r = rr + 16*p;
    *(float4*)&sh[r][c4] = *(const float4*)&in[(size_t)(r0+r)*Cc + c0 + c4];
  }
  __syncthreads();
  #pragma unroll
  for (int p=0;p<4;p++){
    int oc = rr + 16*p;
    u32 w0 = (u32)f2bf(sh[c4+0][oc]) | ((u32)f2bf(sh[c4+1][oc]) << 16);
    u32 w1 = (u32)f2bf(sh[c4+2][oc]) | ((u32)f2bf(sh[c4+3][oc]) << 16);
    uint2 pk; pk.x = w0; pk.y = w1;
    *(uint2*)&out[(size_t)(c0+oc)*R + r0 + c4] = pk;
  }
}

__global__ __launch_bounds__(256)
void k_pre(const float* __restrict__ x, const float* __restrict__ wa,
           const float* __restrict__ wp, u16* __restrict__ xb,
           u16* __restrict__ waT, u16* __restrict__ wpT){
  __shared__ float sh[64][68];
  int bid = blockIdx.x;
  if (bid < 4096){
    int i = bid*256 + threadIdx.x;
    const float4* p = (const float4*)(x) + (size_t)i*2;
    float4 a = p[0], b = p[1];
    uint4 r;
    r.x = (u32)f2bf(a.x) | ((u32)f2bf(a.y) << 16);
    r.y = (u32)f2bf(a.z) | ((u32)f2bf(a.w) << 16);
    r.z = (u32)f2bf(b.x) | ((u32)f2bf(b.y) << 16);
    r.w = (u32)f2bf(b.z) | ((u32)f2bf(b.w) << 16);
    *((uint4*)(xb) + i) = r;
  } else if (bid < 4096 + 768){
    int b2 = bid - 4096;
    tcvt_body(wa, waT, Cn, N1n, b2 % 48, b2 / 48, sh);
  } else {
    int b3 = bid - 4864;
    tcvt_body(wp, wpT, Cn, Cn, b3 % 16, b3 / 16, sh);
  }
}

// ---- 128x128 counted-vmcnt GEMM: C = A . Bt^T + bias ----
template <int MODE>
__global__ __launch_bounds__(256, 2)
void k_gemm2(const u16* __restrict__ A, const u16* __restrict__ Bt,
             const float* __restrict__ bias, void* __restrict__ Cout,
             u16* __restrict__ vt, int Nn_, int byPerXcd)
{
  extern __shared__ char smem[];
  const int nkt = 16;
  int tid = threadIdx.x;
  int wave = tid >> 6, lane = tid & 63, g = lane >> 4, cl = lane & 15;
  int wm = wave >> 1, wn = wave & 1;

  int xcd = blockIdx.x & 7, idx = blockIdx.x >> 3;
  int by = xcd * byPerXcd + (idx % byPerXcd);
  int bx = idx / byPerXcd;
  int m0 = by * 128, n0 = bx * 128;

  int srow = tid >> 3;
  int scolb = (tid & 7) << 4;
  int ssw = scolb ^ ((srow & 7) << 4);
  const char* Agp = (const char*)A  + (size_t)(m0 + srow) * 2048 + ssw;
  const char* Bgp = (const char*)Bt + (size_t)(n0 + srow) * 2048 + ssw;

  #define STG(t_, b_) { \
    const char* ag = Agp + (size_t)(t_)*128; \
    const char* bg = Bgp + (size_t)(t_)*128; \
    char* ab = smem + (b_)*32768 + (wave<<10); \
    char* bb = ab + 16384; \
    gload_lds16(ag,          ab); \
    gload_lds16(ag+ 65536,   ab+4096); \
    gload_lds16(ag+131072,   ab+8192); \
    gload_lds16(ag+196608,   ab+12288); \
    gload_lds16(bg,          bb); \
    gload_lds16(bg+ 65536,   bb+4096); \
    gload_lds16(bg+131072,   bb+8192); \
    gload_lds16(bg+196608,   bb+12288); }

  f32x4 acc[4][4];
  #pragma unroll
  for (int i=0;i<4;i++)
    #pragma unroll
    for (int j=0;j<4;j++) acc[i][j] = (f32x4){0.f,0.f,0.f,0.f};

  STG(0, 0);

  for (int t=0; t<nkt; ++t){
    int b = t & 1;
    if (t+1 < nkt){
      STG(t+1, b^1);
      asm volatile("s_waitcnt vmcnt(8)" ::: "memory");
    } else {
      asm volatile("s_waitcnt vmcnt(0)" ::: "memory");
    }
    BARRIER(); CFENCE();
    const char* Asb = smem + b*32768;
    const char* Bsb = Asb + 16384;
    short8 a[4][2], bq[4][2];
    #pragma unroll
    for (int i=0;i<4;i++){
      int row = wm*64 + i*16 + cl;
      #pragma unroll
      for (int ks=0;ks<2;ks++)
        a[i][ks] = *(const short8*)(Asb + row*128 + ((ks*64 + g*16) ^ ((row&7)<<4)));
    }
    #pragma unroll
    for (int j=0;j<4;j++){
      int row = wn*64 + j*16 + cl;
      #pragma unroll
      for (int ks=0;ks<2;ks++)
        bq[j][ks] = *(const short8*)(Bsb + row*128 + ((ks*64 + g*16) ^ ((row&7)<<4)));
    }
    asm volatile("s_waitcnt lgkmcnt(0)" ::: "memory");
    __builtin_amdgcn_s_setprio(1);
    #pragma unroll
    for (int ks=0;ks<2;ks++)
      #pragma unroll
      for (int i=0;i<4;i++)
        #pragma unroll
        for (int j=0;j<4;j++)
          acc[i][j] = __builtin_amdgcn_mfma_f32_16x16x32_bf16(a[i][ks], bq[j][ks], acc[i][j], 0, 0, 0);
    __builtin_amdgcn_s_setprio(0);
    CFENCE(); BARRIER(); CFENCE();
  }
  #undef STG

  #pragma unroll
  for (int jj=0;jj<4;jj++){
    int col = n0 + wn*64 + jj*16 + cl;
    float bj = bias[col];
    if (MODE == 0){
      #pragma unroll
      for (int i=0;i<4;i++){
        int rowb = m0 + wm*64 + i*16 + g*4;
        #pragma unroll
        for (int r=0;r<4;r++)
          ((float*)Cout)[(size_t)(rowb+r)*Nn_ + col] = acc[i][jj][r] + bj;
      }
    } else if (col < 2*Cn){
      float sc = (col < Cn) ? QSCf : 1.0f;
      #pragma unroll
      for (int i=0;i<4;i++){
        int rowb = m0 + wm*64 + i*16 + g*4;
        #pragma unroll
        for (int r=0;r<4;r++)
          ((u16*)Cout)[(size_t)(rowb+r)*Nn_ + col] = f2bf((acc[i][jj][r] + bj) * sc);
      }
    } else {
      int hd = col - 2*Cn;
      #pragma unroll
      for (int i=0;i<4;i++){
        int rowb = m0 + wm*64 + i*16 + g*4;
        int bb = rowb >> 11, tt = rowb & 2047;
        u16* dst = vt + (((size_t)(bb*16 + (hd>>6)))*64 + (hd&63))*2048 + tt;
        uint2 pk;
        pk.x = (u32)f2bf(acc[i][jj][0]+bj) | ((u32)f2bf(acc[i][jj][1]+bj) << 16);
        pk.y = (u32)f2bf(acc[i][jj][2]+bj) | ((u32)f2bf(acc[i][jj][3]+bj) << 16);
        *(uint2*)dst = pk;
      }
    }
  }
}

// ------- causal flash attention: mirror-paired 64-row q-tiles -------
// grid 1024 x 128 threads (2 waves x 32 q-rows). blk -> (xcd, bh, pi);
// block runs q-tile pi then 31-pi (uniform 33 KV-tiles/block, ZERO tail).
// 32KB LDS -> 4 blocks/CU co-resident, steady 8 waves/CU.
__global__ __launch_bounds__(128, 2)
void k_attn(const u16* __restrict__ qkv, const u16* __restrict__ vt, u16* __restrict__ yb){
  __shared__ __align__(16) u16 Ks[2][64*64];
  __shared__ __align__(16) u16 Vs[2][64*64];
  int tid = threadIdx.x, wave = tid >> 6, lane = tid & 63;
  int ql = lane & 31, hi = lane >> 5;
  int blk = blockIdx.x;
  int xcd = blk & 7, rest = blk >> 3;
  int bh  = xcd + 8*(rest & 7);
  int pi  = rest >> 3;                    // 0..15
  int b = bh >> 4, h = bh & 15;

  const u16* Kbase = qkv + (size_t)b*Tn*N1n + Cn + h*HSn;
  const u16* Vbase = vt  + (size_t)bh*HSn*Tn;

  auto STAGE = [&](int bufi, int kt){
    int kb_ = kt*64;
    #pragma unroll
    for (int it=0; it<4; ++it){
      int off = it*2048 + tid*16;
      int row = off >> 7;
      int cb  = off & 127;
      int gc  = (cb ^ ((row & 7) << 4)) >> 1;
      gload_lds16(Kbase + (size_t)(kb_ + row)*N1n + gc,
                  (char*)&Ks[bufi][0] + it*2048 + (wave << 10));
      gload_lds16(Vbase + (size_t)row*Tn + kb_ + gc,
                  (char*)&Vs[bufi][0] + it*2048 + (wave << 10));
    }
  };

  #pragma unroll 1
  for (int ps=0; ps<2; ++ps){
    int qi  = ps ? (31 - pi) : pi;        // 64-row q-tile index
    int qw0 = qi*64 + wave*32;
    int qg  = qw0 + ql;
    int ntiles = qi + 1;

    // Q B-frags (pre-scaled by QSC in the QKV GEMM epilogue)
    const u16* Qp = qkv + (size_t)(b*Tn + qg)*N1n + h*HSn;
    short8 qf[4];
    #pragma unroll
    for (int dc=0; dc<4; ++dc) qf[dc] = *(const short8*)&Qp[dc*16 + hi*8];

    f32x16 accO[2];
    #pragma unroll
    for (int f=0; f<2; ++f)
      #pragma unroll
      for (int r=0; r<16; ++r) accO[f][r] = 0.f;
    float m_ = -1e30f, l_ = 0.f;

    STAGE(0, 0);
    asm volatile("s_waitcnt vmcnt(0)" ::: "memory");
    __syncthreads();
    int buf = 0;

    for (int kt=0; kt<ntiles; ++kt){
      if (kt+1 < ntiles) STAGE(buf^1, kt+1);
      const char* Ksb = (const char*)&Ks[buf][0];
      const char* Vsb = (const char*)&Vs[buf][0];
      #pragma unroll
      for (int ksub=0; ksub<2; ++ksub){
        int kbase = kt*64 + ksub*32;
        if (kbase <= qw0 + 31){
          f32x16 s;
          #pragma unroll
          for (int r=0; r<16; ++r) s[r] = 0.f;
          __builtin_amdgcn_s_setprio(1);
          #pragma unroll
          for (int dc=0; dc<4; ++dc){
            short8 kf = *(const short8*)(Ksb + ((ksub*32 + ql) << 7)
                            + ((dc*32 + hi*16) ^ ((ql & 7) << 4)));
            s = __builtin_amdgcn_mfma_f32_32x32x16_bf16(kf, qf[dc], s, 0, 0, 0);
          }
          __builtin_amdgcn_s_setprio(0);
          float p[16];
          if (kbase + 31 > qw0){
            #pragma unroll
            for (int r=0; r<16; ++r){
              int krow = kbase + (r&3) + 8*(r>>2) + 4*hi;
              p[r] = (krow > qg) ? -1e30f : s[r];
            }
          } else {
            #pragma unroll
            for (int r=0; r<16; ++r) p[r] = s[r];
          }
          float r0 = fmax3(p[0], p[1], p[2]);
          float r1 = fmax3(p[3], p[4], p[5]);
          float r2 = fmax3(p[6], p[7], p[8]);
          float r3 = fmax3(p[9], p[10], p[11]);
          float r4 = fmax3(p[12], p[13], p[14]);
          float tm = fmaxf(fmax3(r0, r1, r2), fmax3(r3, r4, p[15]));
          { u32 ua = __float_as_uint(tm), ub = ua; plswap(ua, ub);
            tm = fmaxf(__uint_as_float(ua), __uint_as_float(ub)); }
          if (!__all(tm - m_ <= 8.0f)){
            float mn = fmaxf(m_, tm);
            float al = fexp2(m_ - mn);
            m_ = mn; l_ *= al;
            #pragma unroll
            for (int f=0; f<2; ++f)
              #pragma unroll
              for (int r=0; r<16; ++r) accO[f][r] *= al;
          }
          float ls = 0.f;
          #pragma unroll
          for (int r=0; r<16; ++r){ float e = fexp2(p[r] - m_); p[r] = e; ls += e; }
          { u32 ua = __float_as_uint(ls), ub = ua; plswap(ua, ub);
            l_ += __uint_as_float(ua) + __uint_as_float(ub); }
          #pragma unroll
          for (int ks=0; ks<2; ++ks){
            int pb = ks*8;
            u32 w0 = pkbf(p[pb+0], p[pb+1]);
            u32 w1 = pkbf(p[pb+2], p[pb+3]);
            u32 w2 = pkbf(p[pb+4], p[pb+5]);
            u32 w3 = pkbf(p[pb+6], p[pb+7]);
            plswap(w0, w2);
            plswap(w1, w3);
            union { u32 w[4]; short8 v; } pu;
            pu.w[0] = w0; pu.w[1] = w1; pu.w[2] = w2; pu.w[3] = w3;
            __builtin_amdgcn_s_setprio(1);
            #pragma unroll
            for (int f=0; f<2; ++f){
              short8 vf = *(const short8*)(Vsb + ((f*32 + ql) << 7)
                              + ((ksub*64 + ks*32 + hi*16) ^ ((ql & 7) << 4)));
              accO[f] = __builtin_amdgcn_mfma_f32_32x32x16_bf16(vf, pu.v, accO[f], 0, 0, 0);
            }
            __builtin_amdgcn_s_setprio(0);
          }
        }
      }
      asm volatile("s_waitcnt vmcnt(0)" ::: "memory");
      __syncthreads();
      buf ^= 1;
    }

    float rl = 1.0f / l_;
    u16* yp = yb + (size_t)(b*Tn + qg)*Cn + h*HSn;
    #pragma unroll
    for (int f=0; f<2; ++f)
      #pragma unroll
      for (int rq=0; rq<4; ++rq){
        int d0 = f*32 + rq*8 + hi*4;
        float v0 = accO[f][rq*4+0]*rl, v1 = accO[f][rq*4+1]*rl;
        float v2 = accO[f][rq*4+2]*rl, v3 = accO[f][rq*4+3]*rl;
        uint2 pk2;
        pk2.x = (u32)f2bf(v0) | ((u32)f2bf(v1) << 16);
        pk2.y = (u32)f2bf(v2) | ((u32)f2bf(v3) << 16);
        *(uint2*)&yp[d0] = pk2;
      }
  }
}

extern "C" void kernel_launch(void* const* d_in, const int* in_sizes, int n_in,
                              void* d_out, int out_size, void* d_ws, size_t ws_size,
                              hipStream_t stream)
{
  const float* x      = (const float*)d_in[0];
  const float* w_attn = (const float*)d_in[1];
  const float* b_attn = (const float*)d_in[2];
  const float* w_proj = (const float*)d_in[3];
  const float* b_proj = (const float*)d_in[4];
  float* out = (float*)d_out;
  char* ws = (char*)d_ws;

  size_t off = 0;
  u16* xb  = (u16*)(ws + off); off += (size_t)Mn*Cn*2;
  u16* waT = (u16*)(ws + off); off += (size_t)N1n*Cn*2;
  u16* wpT = (u16*)(ws + off); off += (size_t)Cn*Cn*2;
  u16* qkv = (u16*)(ws + off); off += (size_t)Mn*N1n*2;
  u16* vt  = (u16*)(ws + off); off += (size_t)Bn*Hn*HSn*Tn*2;
  u16* yb  = (u16*)(ws + off); off += (size_t)Mn*Cn*2;

  (void)hipFuncSetAttribute((const void*)k_gemm2<1>,
        hipFuncAttributeMaxDynamicSharedMemorySize, 65536);
  (void)hipFuncSetAttribute((const void*)k_gemm2<0>,
        hipFuncAttributeMaxDynamicSharedMemorySize, 65536);

  k_pre<<<dim3(5120), 256, 0, stream>>>(x, w_attn, w_proj, xb, waT, wpT);
  k_gemm2<1><<<dim3((Mn/128)*(N1n/128)), 256, 65536, stream>>>(xb, waT, b_attn, qkv, vt, N1n, 8);
  k_attn<<<dim3(1024), 128, 0, stream>>>(qkv, vt, yb);
  k_gemm2<0><<<dim3((Mn/128)*(Cn/128)), 256, 65536, stream>>>(yb, wpT, b_proj, out, nullptr, Cn, 8);
}

// Round 13
// 141.348 us; speedup vs baseline: 1.1297x; 1.0901x over previous
//
#include <hip/hip_runtime.h>
#include <stdint.h>

#define Bn 4
#define Tn 2048
#define Cn 1024
#define Hn 16
#define HSn 64
#define Mn (Bn*Tn)
#define N1n (3*Cn)

typedef unsigned short u16;
typedef unsigned int u32;
typedef __attribute__((ext_vector_type(8))) short short8;
typedef __attribute__((ext_vector_type(4))) float f32x4;
typedef __attribute__((ext_vector_type(16))) float f32x16;

#define QSCf (0.125f * 1.44269504f)

__device__ __forceinline__ u16 f2bf(float f){
  u32 u = __float_as_uint(f);
  u += 0x7fffu + ((u >> 16) & 1u);
  return (u16)(u >> 16);
}

__device__ __forceinline__ u32 pkbf(float lo, float hi_){
  u32 r; asm("v_cvt_pk_bf16_f32 %0, %1, %2" : "=v"(r) : "v"(lo), "v"(hi_)); return r;
}

__device__ __forceinline__ float fexp2(float x){
  float r; asm("v_exp_f32 %0, %1" : "=v"(r) : "v"(x)); return r;
}

__device__ __forceinline__ float fmax3(float a, float b, float c){
  float r; asm("v_max3_f32 %0, %1, %2, %3" : "=v"(r) : "v"(a), "v"(b), "v"(c)); return r;
}

__device__ __forceinline__ void plswap(u32 &a, u32 &b){
  auto r = __builtin_amdgcn_permlane32_swap(a, b, false, false);
  a = r[0]; b = r[1];
}

__device__ __forceinline__ void gload_lds16(const void* g, void* l){
  __builtin_amdgcn_global_load_lds(
      (const __attribute__((address_space(1))) u32*)g,
      (__attribute__((address_space(3))) u32*)l, 16, 0, 0);
}

#define BARRIER() __builtin_amdgcn_s_barrier()
#define CFENCE() asm volatile("" ::: "memory")

// ---- fused pre-pass: x->bf16 | w_attn^T->bf16 | w_proj^T->bf16 ----
__device__ __forceinline__ void tcvt_body(const float* __restrict__ in,
                                          u16* __restrict__ out,
                                          int R, int Cc, int bxx, int byy,
                                          float sh[64][68]){
  int tid = threadIdx.x;
  int c0 = bxx*64, r0 = byy*64;
  int rr = tid >> 4, c4 = (tid & 15) * 4;
  #pragma unroll
  for (int p=0;p<4;p++){
    int r = rr + 16*p;
    *(float4*)&sh[r][c4] = *(const float4*)&in[(size_t)(r0+r)*Cc + c0 + c4];
  }
  __syncthreads();
  #pragma unroll
  for (int p=0;p<4;p++){
    int oc = rr + 16*p;
    u32 w0 = (u32)f2bf(sh[c4+0][oc]) | ((u32)f2bf(sh[c4+1][oc]) << 16);
    u32 w1 = (u32)f2bf(sh[c4+2][oc]) | ((u32)f2bf(sh[c4+3][oc]) << 16);
    uint2 pk; pk.x = w0; pk.y = w1;
    *(uint2*)&out[(size_t)(c0+oc)*R + r0 + c4] = pk;
  }
}

__global__ __launch_bounds__(256)
void k_pre(const float* __restrict__ x, const float* __restrict__ wa,
           const float* __restrict__ wp, u16* __restrict__ xb,
           u16* __restrict__ waT, u16* __restrict__ wpT){
  __shared__ float sh[64][68];
  int bid = blockIdx.x;
  if (bid < 4096){
    int i = bid*256 + threadIdx.x;
    const float4* p = (const float4*)(x) + (size_t)i*2;
    float4 a = p[0], b = p[1];
    uint4 r;
    r.x = (u32)f2bf(a.x) | ((u32)f2bf(a.y) << 16);
    r.y = (u32)f2bf(a.z) | ((u32)f2bf(a.w) << 16);
    r.z = (u32)f2bf(b.x) | ((u32)f2bf(b.y) << 16);
    r.w = (u32)f2bf(b.z) | ((u32)f2bf(b.w) << 16);
    *((uint4*)(xb) + i) = r;
  } else if (bid < 4096 + 768){
    int b2 = bid - 4096;
    tcvt_body(wa, waT, Cn, N1n, b2 % 48, b2 / 48, sh);
  } else {
    int b3 = bid - 4864;
    tcvt_body(wp, wpT, Cn, Cn, b3 % 16, b3 / 16, sh);
  }
}

// ---- 128x128 counted-vmcnt GEMM: C = A . Bt^T + bias ----
template <int MODE>
__global__ __launch_bounds__(256, 2)
void k_gemm2(const u16* __restrict__ A, const u16* __restrict__ Bt,
             const float* __restrict__ bias, void* __restrict__ Cout,
             u16* __restrict__ vt, int Nn_, int byPerXcd)
{
  extern __shared__ char smem[];
  const int nkt = 16;
  int tid = threadIdx.x;
  int wave = tid >> 6, lane = tid & 63, g = lane >> 4, cl = lane & 15;
  int wm = wave >> 1, wn = wave & 1;

  int xcd = blockIdx.x & 7, idx = blockIdx.x >> 3;
  int by = xcd * byPerXcd + (idx % byPerXcd);
  int bx = idx / byPerXcd;
  int m0 = by * 128, n0 = bx * 128;

  int srow = tid >> 3;
  int scolb = (tid & 7) << 4;
  int ssw = scolb ^ ((srow & 7) << 4);
  const char* Agp = (const char*)A  + (size_t)(m0 + srow) * 2048 + ssw;
  const char* Bgp = (const char*)Bt + (size_t)(n0 + srow) * 2048 + ssw;

  #define STG(t_, b_) { \
    const char* ag = Agp + (size_t)(t_)*128; \
    const char* bg = Bgp + (size_t)(t_)*128; \
    char* ab = smem + (b_)*32768 + (wave<<10); \
    char* bb = ab + 16384; \
    gload_lds16(ag,          ab); \
    gload_lds16(ag+ 65536,   ab+4096); \
    gload_lds16(ag+131072,   ab+8192); \
    gload_lds16(ag+196608,   ab+12288); \
    gload_lds16(bg,          bb); \
    gload_lds16(bg+ 65536,   bb+4096); \
    gload_lds16(bg+131072,   bb+8192); \
    gload_lds16(bg+196608,   bb+12288); }

  f32x4 acc[4][4];
  #pragma unroll
  for (int i=0;i<4;i++)
    #pragma unroll
    for (int j=0;j<4;j++) acc[i][j] = (f32x4){0.f,0.f,0.f,0.f};

  STG(0, 0);

  for (int t=0; t<nkt; ++t){
    int b = t & 1;
    if (t+1 < nkt){
      STG(t+1, b^1);
      asm volatile("s_waitcnt vmcnt(8)" ::: "memory");
    } else {
      asm volatile("s_waitcnt vmcnt(0)" ::: "memory");
    }
    BARRIER(); CFENCE();
    const char* Asb = smem + b*32768;
    const char* Bsb = Asb + 16384;
    short8 a[4][2], bq[4][2];
    #pragma unroll
    for (int i=0;i<4;i++){
      int row = wm*64 + i*16 + cl;
      #pragma unroll
      for (int ks=0;ks<2;ks++)
        a[i][ks] = *(const short8*)(Asb + row*128 + ((ks*64 + g*16) ^ ((row&7)<<4)));
    }
    #pragma unroll
    for (int j=0;j<4;j++){
      int row = wn*64 + j*16 + cl;
      #pragma unroll
      for (int ks=0;ks<2;ks++)
        bq[j][ks] = *(const short8*)(Bsb + row*128 + ((ks*64 + g*16) ^ ((row&7)<<4)));
    }
    asm volatile("s_waitcnt lgkmcnt(0)" ::: "memory");
    __builtin_amdgcn_s_setprio(1);
    #pragma unroll
    for (int ks=0;ks<2;ks++)
      #pragma unroll
      for (int i=0;i<4;i++)
        #pragma unroll
        for (int j=0;j<4;j++)
          acc[i][j] = __builtin_amdgcn_mfma_f32_16x16x32_bf16(a[i][ks], bq[j][ks], acc[i][j], 0, 0, 0);
    __builtin_amdgcn_s_setprio(0);
    CFENCE(); BARRIER(); CFENCE();
  }
  #undef STG

  #pragma unroll
  for (int jj=0;jj<4;jj++){
    int col = n0 + wn*64 + jj*16 + cl;
    float bj = bias[col];
    if (MODE == 0){
      #pragma unroll
      for (int i=0;i<4;i++){
        int rowb = m0 + wm*64 + i*16 + g*4;
        #pragma unroll
        for (int r=0;r<4;r++)
          ((float*)Cout)[(size_t)(rowb+r)*Nn_ + col] = acc[i][jj][r] + bj;
      }
    } else if (col < 2*Cn){
      float sc = (col < Cn) ? QSCf : 1.0f;
      #pragma unroll
      for (int i=0;i<4;i++){
        int rowb = m0 + wm*64 + i*16 + g*4;
        #pragma unroll
        for (int r=0;r<4;r++)
          ((u16*)Cout)[(size_t)(rowb+r)*Nn_ + col] = f2bf((acc[i][jj][r] + bj) * sc);
      }
    } else {
      int hd = col - 2*Cn;
      #pragma unroll
      for (int i=0;i<4;i++){
        int rowb = m0 + wm*64 + i*16 + g*4;
        int bb = rowb >> 11, tt = rowb & 2047;
        u16* dst = vt + (((size_t)(bb*16 + (hd>>6)))*64 + (hd&63))*2048 + tt;
        uint2 pk;
        pk.x = (u32)f2bf(acc[i][jj][0]+bj) | ((u32)f2bf(acc[i][jj][1]+bj) << 16);
        pk.y = (u32)f2bf(acc[i][jj][2]+bj) | ((u32)f2bf(acc[i][jj][3]+bj) << 16);
        *(uint2*)dst = pk;
      }
    }
  }
}

// ------- causal flash attention: R8 launch shape + batched 64-wide tiles -------
// grid 1024 x 256 thr: blk -> (xcd, bh, qt), per-CU balanced qt sets; 4 blocks/CU.
// Interior KV tiles processed 64-wide in one fused softmax pass (shared m_/l_):
// 8 QK MFMA -> combined max/rescale/exp over 32 vals -> 8 PV MFMA.
__global__ __launch_bounds__(256, 4)
void k_attn(const u16* __restrict__ qkv, const u16* __restrict__ vt, u16* __restrict__ yb){
  __shared__ __align__(16) u16 Ks[2][64*64];
  __shared__ __align__(16) u16 Vs[2][64*64];
  int tid = threadIdx.x, wave = tid >> 6, lane = tid & 63;
  int ql = lane & 31, hi = lane >> 5;
  int blk = blockIdx.x;
  int xcd = blk & 7, rest = blk >> 3;
  int bh  = xcd + 8*(rest & 7);
  int qtsel = rest >> 3;
  int a_ = qtsel & 3, g_ = qtsel >> 2;
  int qt = (g_==0) ? (15 - a_) : (g_==1) ? (7 - a_) : (g_==2) ? (8 + a_) : a_;
  int b = bh >> 4, h = bh & 15;

  const u16* Kbase = qkv + (size_t)b*Tn*N1n + Cn + h*HSn;
  const u16* Vbase = vt  + (size_t)bh*HSn*Tn;

  auto STAGE = [&](int bufi, int kt){
    int kb_ = kt*64;
    #pragma unroll
    for (int it=0; it<2; ++it){
      int off = it*4096 + tid*16;
      int row = off >> 7;
      int cb  = off & 127;
      int gc  = (cb ^ ((row & 7) << 4)) >> 1;
      gload_lds16(Kbase + (size_t)(kb_ + row)*N1n + gc,
                  (char*)&Ks[bufi][0] + it*4096 + (wave << 10));
      gload_lds16(Vbase + (size_t)row*Tn + kb_ + gc,
                  (char*)&Vs[bufi][0] + it*4096 + (wave << 10));
    }
  };

  int q0 = qt * 128;
  int qw0 = q0 + wave*32;
  int qg  = qw0 + ql;
  int ntiles = 2*qt + 2;

  // Q B-frags: pre-scaled by QSC in the QKV GEMM epilogue
  const u16* Qp = qkv + (size_t)(b*Tn + qg)*N1n + h*HSn;
  short8 qf[4];
  #pragma unroll
  for (int dc=0; dc<4; ++dc) qf[dc] = *(const short8*)&Qp[dc*16 + hi*8];

  f32x16 accO[2];
  #pragma unroll
  for (int f=0; f<2; ++f)
    #pragma unroll
    for (int r=0; r<16; ++r) accO[f][r] = 0.f;
  float m_ = -1e30f, l_ = 0.f;

  int xsw = (ql & 7) << 4;

  // pack 8 P-values (f32) starting at sX[pb] into one B-frag and do 2 PV MFMAs
  auto PVS = [&](const f32x16& sx, int pb, int voff, const char* Vsb){
    u32 w0 = pkbf(sx[pb+0], sx[pb+1]);
    u32 w1 = pkbf(sx[pb+2], sx[pb+3]);
    u32 w2 = pkbf(sx[pb+4], sx[pb+5]);
    u32 w3 = pkbf(sx[pb+6], sx[pb+7]);
    plswap(w0, w2);
    plswap(w1, w3);
    union { u32 w[4]; short8 v; } pu;
    pu.w[0] = w0; pu.w[1] = w1; pu.w[2] = w2; pu.w[3] = w3;
    __builtin_amdgcn_s_setprio(1);
    #pragma unroll
    for (int f=0; f<2; ++f){
      short8 vf = *(const short8*)(Vsb + ((f*32 + ql) << 7) + ((voff + hi*16) ^ xsw));
      accO[f] = __builtin_amdgcn_mfma_f32_32x32x16_bf16(vf, pu.v, accO[f], 0, 0, 0);
    }
    __builtin_amdgcn_s_setprio(0);
  };

  STAGE(0, 0);
  asm volatile("s_waitcnt vmcnt(0)" ::: "memory");
  __syncthreads();
  int buf = 0;

  for (int kt=0; kt<ntiles; ++kt){
    if (kt+1 < ntiles) STAGE(buf^1, kt+1);
    const char* Ksb = (const char*)&Ks[buf][0];
    const char* Vsb = (const char*)&Vs[buf][0];
    if (kt*64 + 63 <= qw0){
      // ---------- fast path: full 64-wide tile, fused softmax ----------
      f32x16 s0, s1;
      #pragma unroll
      for (int r=0; r<16; ++r){ s0[r]=0.f; s1[r]=0.f; }
      __builtin_amdgcn_s_setprio(1);
      #pragma unroll
      for (int dc=0; dc<4; ++dc){
        short8 kf0 = *(const short8*)(Ksb + ((     ql) << 7) + ((dc*32 + hi*16) ^ xsw));
        short8 kf1 = *(const short8*)(Ksb + ((32 + ql) << 7) + ((dc*32 + hi*16) ^ xsw));
        s0 = __builtin_amdgcn_mfma_f32_32x32x16_bf16(kf0, qf[dc], s0, 0, 0, 0);
        s1 = __builtin_amdgcn_mfma_f32_32x32x16_bf16(kf1, qf[dc], s1, 0, 0, 0);
      }
      __builtin_amdgcn_s_setprio(0);
      // combined row-max over 32 values
      float a0 = fmax3(s0[0], s0[1], s0[2]);
      float a1 = fmax3(s0[3], s0[4], s0[5]);
      float a2 = fmax3(s0[6], s0[7], s0[8]);
      float a3 = fmax3(s0[9], s0[10], s0[11]);
      float a4 = fmax3(s0[12], s0[13], s0[14]);
      float ta = fmaxf(fmax3(a0, a1, a2), fmax3(a3, a4, s0[15]));
      float b0 = fmax3(s1[0], s1[1], s1[2]);
      float b1 = fmax3(s1[3], s1[4], s1[5]);
      float b2 = fmax3(s1[6], s1[7], s1[8]);
      float b3 = fmax3(s1[9], s1[10], s1[11]);
      float b4 = fmax3(s1[12], s1[13], s1[14]);
      float tb = fmaxf(fmax3(b0, b1, b2), fmax3(b3, b4, s1[15]));
      float tm = fmaxf(ta, tb);
      { u32 ua = __float_as_uint(tm), ub = ua; plswap(ua, ub);
        tm = fmaxf(__uint_as_float(ua), __uint_as_float(ub)); }
      if (!__all(tm - m_ <= 8.0f)){
        float mn = fmaxf(m_, tm);
        float al = fexp2(m_ - mn);
        m_ = mn; l_ *= al;
        #pragma unroll
        for (int f=0; f<2; ++f)
          #pragma unroll
          for (int r=0; r<16; ++r) accO[f][r] *= al;
      }
      float ls = 0.f;
      #pragma unroll
      for (int r=0; r<16; ++r){ float e = fexp2(s0[r] - m_); s0[r] = e; ls += e; }
      #pragma unroll
      for (int r=0; r<16; ++r){ float e = fexp2(s1[r] - m_); s1[r] = e; ls += e; }
      { u32 ua = __float_as_uint(ls), ub = ua; plswap(ua, ub);
        l_ += __uint_as_float(ua) + __uint_as_float(ub); }
      // PV: 4 slices of 16 k
      PVS(s0, 0,  0, Vsb);
      PVS(s0, 8, 32, Vsb);
      PVS(s1, 0, 64, Vsb);
      PVS(s1, 8, 96, Vsb);
    } else {
      // ---------- diagonal tile: per-ksub guarded path (R8 body) ----------
      #pragma unroll
      for (int ksub=0; ksub<2; ++ksub){
        int kbase = kt*64 + ksub*32;
        if (kbase <= qw0 + 31){
          f32x16 s;
          #pragma unroll
          for (int r=0; r<16; ++r) s[r] = 0.f;
          __builtin_amdgcn_s_setprio(1);
          #pragma unroll
          for (int dc=0; dc<4; ++dc){
            short8 kf = *(const short8*)(Ksb + ((ksub*32 + ql) << 7)
                            + ((dc*32 + hi*16) ^ xsw));
            s = __builtin_amdgcn_mfma_f32_32x32x16_bf16(kf, qf[dc], s, 0, 0, 0);
          }
          __builtin_amdgcn_s_setprio(0);
          if (kbase + 31 > qw0){
            #pragma unroll
            for (int r=0; r<16; ++r){
              int krow = kbase + (r&3) + 8*(r>>2) + 4*hi;
              s[r] = (krow > qg) ? -1e30f : s[r];
            }
          }
          float r0 = fmax3(s[0], s[1], s[2]);
          float r1 = fmax3(s[3], s[4], s[5]);
          float r2 = fmax3(s[6], s[7], s[8]);
          float r3 = fmax3(s[9], s[10], s[11]);
          float r4 = fmax3(s[12], s[13], s[14]);
          float tm = fmaxf(fmax3(r0, r1, r2), fmax3(r3, r4, s[15]));
          { u32 ua = __float_as_uint(tm), ub = ua; plswap(ua, ub);
            tm = fmaxf(__uint_as_float(ua), __uint_as_float(ub)); }
          if (!__all(tm - m_ <= 8.0f)){
            float mn = fmaxf(m_, tm);
            float al = fexp2(m_ - mn);
            m_ = mn; l_ *= al;
            #pragma unroll
            for (int f=0; f<2; ++f)
              #pragma unroll
              for (int r=0; r<16; ++r) accO[f][r] *= al;
          }
          float ls = 0.f;
          #pragma unroll
          for (int r=0; r<16; ++r){ float e = fexp2(s[r] - m_); s[r] = e; ls += e; }
          { u32 ua = __float_as_uint(ls), ub = ua; plswap(ua, ub);
            l_ += __uint_as_float(ua) + __uint_as_float(ub); }
          PVS(s, 0, ksub*64,      Vsb);
          PVS(s, 8, ksub*64 + 32, Vsb);
        }
      }
    }
    asm volatile("s_waitcnt vmcnt(0)" ::: "memory");
    __syncthreads();
    buf ^= 1;
  }

  float rl = 1.0f / l_;
  u16* yp = yb + (size_t)(b*Tn + qg)*Cn + h*HSn;
  #pragma unroll
  for (int f=0; f<2; ++f)
    #pragma unroll
    for (int rq=0; rq<4; ++rq){
      int d0 = f*32 + rq*8 + hi*4;
      float v0 = accO[f][rq*4+0]*rl, v1 = accO[f][rq*4+1]*rl;
      float v2 = accO[f][rq*4+2]*rl, v3 = accO[f][rq*4+3]*rl;
      uint2 pk2;
      pk2.x = (u32)f2bf(v0) | ((u32)f2bf(v1) << 16);
      pk2.y = (u32)f2bf(v2) | ((u32)f2bf(v3) << 16);
      *(uint2*)&yp[d0] = pk2;
    }
}

extern "C" void kernel_launch(void* const* d_in, const int* in_sizes, int n_in,
                              void* d_out, int out_size, void* d_ws, size_t ws_size,
                              hipStream_t stream)
{
  const float* x      = (const float*)d_in[0];
  const float* w_attn = (const float*)d_in[1];
  const float* b_attn = (const float*)d_in[2];
  const float* w_proj = (const float*)d_in[3];
  const float* b_proj = (const float*)d_in[4];
  float* out = (float*)d_out;
  char* ws = (char*)d_ws;

  size_t off = 0;
  u16* xb  = (u16*)(ws + off); off += (size_t)Mn*Cn*2;
  u16* waT = (u16*)(ws + off); off += (size_t)N1n*Cn*2;
  u16* wpT = (u16*)(ws + off); off += (size_t)Cn*Cn*2;
  u16* qkv = (u16*)(ws + off); off += (size_t)Mn*N1n*2;
  u16* vt  = (u16*)(ws + off); off += (size_t)Bn*Hn*HSn*Tn*2;
  u16* yb  = (u16*)(ws + off); off += (size_t)Mn*Cn*2;

  (void)hipFuncSetAttribute((const void*)k_gemm2<1>,
        hipFuncAttributeMaxDynamicSharedMemorySize, 65536);
  (void)hipFuncSetAttribute((const void*)k_gemm2<0>,
        hipFuncAttributeMaxDynamicSharedMemorySize, 65536);

  k_pre<<<dim3(5120), 256, 0, stream>>>(x, w_attn, w_proj, xb, waT, wpT);
  k_gemm2<1><<<dim3((Mn/128)*(N1n/128)), 256, 65536, stream>>>(xb, waT, b_attn, qkv, vt, N1n, 8);
  k_attn<<<dim3(1024), 256, 0, stream>>>(qkv, vt, yb);
  k_gemm2<0><<<dim3((Mn/128)*(Cn/128)), 256, 65536, stream>>>(yb, wpT, b_proj, out, nullptr, Cn, 8);
}

// Round 14
// 141.210 us; speedup vs baseline: 1.1308x; 1.0010x over previous
//
#include <hip/hip_runtime.h>
#include <stdint.h>

#define Bn 4
#define Tn 2048
#define Cn 1024
#define Hn 16
#define HSn 64
#define Mn (Bn*Tn)
#define N1n (3*Cn)

typedef unsigned short u16;
typedef unsigned int u32;
typedef __attribute__((ext_vector_type(8))) short short8;
typedef __attribute__((ext_vector_type(4))) float f32x4;
typedef __attribute__((ext_vector_type(16))) float f32x16;

#define QSCf (0.125f * 1.44269504f)

__device__ __forceinline__ u16 f2bf(float f){
  u32 u = __float_as_uint(f);
  u += 0x7fffu + ((u >> 16) & 1u);
  return (u16)(u >> 16);
}

__device__ __forceinline__ u32 pkbf(float lo, float hi_){
  u32 r; asm("v_cvt_pk_bf16_f32 %0, %1, %2" : "=v"(r) : "v"(lo), "v"(hi_)); return r;
}

__device__ __forceinline__ float fexp2(float x){
  float r; asm("v_exp_f32 %0, %1" : "=v"(r) : "v"(x)); return r;
}

__device__ __forceinline__ float fmax3(float a, float b, float c){
  float r; asm("v_max3_f32 %0, %1, %2, %3" : "=v"(r) : "v"(a), "v"(b), "v"(c)); return r;
}

__device__ __forceinline__ void plswap(u32 &a, u32 &b){
  auto r = __builtin_amdgcn_permlane32_swap(a, b, false, false);
  a = r[0]; b = r[1];
}

__device__ __forceinline__ void gload_lds16(const void* g, void* l){
  __builtin_amdgcn_global_load_lds(
      (const __attribute__((address_space(1))) u32*)g,
      (__attribute__((address_space(3))) u32*)l, 16, 0, 0);
}

#define BARRIER() __builtin_amdgcn_s_barrier()
#define CFENCE() asm volatile("" ::: "memory")

// ---- fused pre-pass: x->bf16 | w_attn^T->bf16 | w_proj^T->bf16 ----
__device__ __forceinline__ void tcvt_body(const float* __restrict__ in,
                                          u16* __restrict__ out,
                                          int R, int Cc, int bxx, int byy,
                                          float sh[64][68]){
  int tid = threadIdx.x;
  int c0 = bxx*64, r0 = byy*64;
  int rr = tid >> 4, c4 = (tid & 15) * 4;
  #pragma unroll
  for (int p=0;p<4;p++){
    int r = rr + 16*p;
    *(float4*)&sh[r][c4] = *(const float4*)&in[(size_t)(r0+r)*Cc + c0 + c4];
  }
  __syncthreads();
  #pragma unroll
  for (int p=0;p<4;p++){
    int oc = rr + 16*p;
    u32 w0 = (u32)f2bf(sh[c4+0][oc]) | ((u32)f2bf(sh[c4+1][oc]) << 16);
    u32 w1 = (u32)f2bf(sh[c4+2][oc]) | ((u32)f2bf(sh[c4+3][oc]) << 16);
    uint2 pk; pk.x = w0; pk.y = w1;
    *(uint2*)&out[(size_t)(c0+oc)*R + r0 + c4] = pk;
  }
}

__global__ __launch_bounds__(256)
void k_pre(const float* __restrict__ x, const float* __restrict__ wa,
           const float* __restrict__ wp, u16* __restrict__ xb,
           u16* __restrict__ waT, u16* __restrict__ wpT){
  __shared__ float sh[64][68];
  int bid = blockIdx.x;
  if (bid < 4096){
    int i = bid*256 + threadIdx.x;
    const float4* p = (const float4*)(x) + (size_t)i*2;
    float4 a = p[0], b = p[1];
    uint4 r;
    r.x = (u32)f2bf(a.x) | ((u32)f2bf(a.y) << 16);
    r.y = (u32)f2bf(a.z) | ((u32)f2bf(a.w) << 16);
    r.z = (u32)f2bf(b.x) | ((u32)f2bf(b.y) << 16);
    r.w = (u32)f2bf(b.z) | ((u32)f2bf(b.w) << 16);
    *((uint4*)(xb) + i) = r;
  } else if (bid < 4096 + 768){
    int b2 = bid - 4096;
    tcvt_body(wa, waT, Cn, N1n, b2 % 48, b2 / 48, sh);
  } else {
    int b3 = bid - 4864;
    tcvt_body(wp, wpT, Cn, Cn, b3 % 16, b3 / 16, sh);
  }
}

// ---- 128x128 counted-vmcnt GEMM: C = A . Bt^T + bias ----
// (R13 minus the forced lgkmcnt(0): let the compiler interleave MFMA with
// trailing ds_reads via its own fine-grained lgkmcnt(N).)
template <int MODE>
__global__ __launch_bounds__(256, 2)
void k_gemm2(const u16* __restrict__ A, const u16* __restrict__ Bt,
             const float* __restrict__ bias, void* __restrict__ Cout,
             u16* __restrict__ vt, int Nn_, int byPerXcd)
{
  extern __shared__ char smem[];
  const int nkt = 16;
  int tid = threadIdx.x;
  int wave = tid >> 6, lane = tid & 63, g = lane >> 4, cl = lane & 15;
  int wm = wave >> 1, wn = wave & 1;

  int xcd = blockIdx.x & 7, idx = blockIdx.x >> 3;
  int by = xcd * byPerXcd + (idx % byPerXcd);
  int bx = idx / byPerXcd;
  int m0 = by * 128, n0 = bx * 128;

  int srow = tid >> 3;
  int scolb = (tid & 7) << 4;
  int ssw = scolb ^ ((srow & 7) << 4);
  const char* Agp = (const char*)A  + (size_t)(m0 + srow) * 2048 + ssw;
  const char* Bgp = (const char*)Bt + (size_t)(n0 + srow) * 2048 + ssw;

  #define STG(t_, b_) { \
    const char* ag = Agp + (size_t)(t_)*128; \
    const char* bg = Bgp + (size_t)(t_)*128; \
    char* ab = smem + (b_)*32768 + (wave<<10); \
    char* bb = ab + 16384; \
    gload_lds16(ag,          ab); \
    gload_lds16(ag+ 65536,   ab+4096); \
    gload_lds16(ag+131072,   ab+8192); \
    gload_lds16(ag+196608,   ab+12288); \
    gload_lds16(bg,          bb); \
    gload_lds16(bg+ 65536,   bb+4096); \
    gload_lds16(bg+131072,   bb+8192); \
    gload_lds16(bg+196608,   bb+12288); }

  f32x4 acc[4][4];
  #pragma unroll
  for (int i=0;i<4;i++)
    #pragma unroll
    for (int j=0;j<4;j++) acc[i][j] = (f32x4){0.f,0.f,0.f,0.f};

  STG(0, 0);

  for (int t=0; t<nkt; ++t){
    int b = t & 1;
    if (t+1 < nkt){
      STG(t+1, b^1);
      asm volatile("s_waitcnt vmcnt(8)" ::: "memory");
    } else {
      asm volatile("s_waitcnt vmcnt(0)" ::: "memory");
    }
    BARRIER(); CFENCE();
    const char* Asb = smem + b*32768;
    const char* Bsb = Asb + 16384;
    short8 a[4][2], bq[4][2];
    #pragma unroll
    for (int i=0;i<4;i++){
      int row = wm*64 + i*16 + cl;
      #pragma unroll
      for (int ks=0;ks<2;ks++)
        a[i][ks] = *(const short8*)(Asb + row*128 + ((ks*64 + g*16) ^ ((row&7)<<4)));
    }
    #pragma unroll
    for (int j=0;j<4;j++){
      int row = wn*64 + j*16 + cl;
      #pragma unroll
      for (int ks=0;ks<2;ks++)
        bq[j][ks] = *(const short8*)(Bsb + row*128 + ((ks*64 + g*16) ^ ((row&7)<<4)));
    }
    __builtin_amdgcn_s_setprio(1);
    #pragma unroll
    for (int ks=0;ks<2;ks++)
      #pragma unroll
      for (int i=0;i<4;i++)
        #pragma unroll
        for (int j=0;j<4;j++)
          acc[i][j] = __builtin_amdgcn_mfma_f32_16x16x32_bf16(a[i][ks], bq[j][ks], acc[i][j], 0, 0, 0);
    __builtin_amdgcn_s_setprio(0);
    CFENCE(); BARRIER(); CFENCE();
  }
  #undef STG

  #pragma unroll
  for (int jj=0;jj<4;jj++){
    int col = n0 + wn*64 + jj*16 + cl;
    float bj = bias[col];
    if (MODE == 0){
      #pragma unroll
      for (int i=0;i<4;i++){
        int rowb = m0 + wm*64 + i*16 + g*4;
        #pragma unroll
        for (int r=0;r<4;r++)
          ((float*)Cout)[(size_t)(rowb+r)*Nn_ + col] = acc[i][jj][r] + bj;
      }
    } else if (col < 2*Cn){
      float sc = (col < Cn) ? QSCf : 1.0f;
      #pragma unroll
      for (int i=0;i<4;i++){
        int rowb = m0 + wm*64 + i*16 + g*4;
        #pragma unroll
        for (int r=0;r<4;r++)
          ((u16*)Cout)[(size_t)(rowb+r)*Nn_ + col] = f2bf((acc[i][jj][r] + bj) * sc);
      }
    } else {
      int hd = col - 2*Cn;
      #pragma unroll
      for (int i=0;i<4;i++){
        int rowb = m0 + wm*64 + i*16 + g*4;
        int bb = rowb >> 11, tt = rowb & 2047;
        u16* dst = vt + (((size_t)(bb*16 + (hd>>6)))*64 + (hd&63))*2048 + tt;
        uint2 pk;
        pk.x = (u32)f2bf(acc[i][jj][0]+bj) | ((u32)f2bf(acc[i][jj][1]+bj) << 16);
        pk.y = (u32)f2bf(acc[i][jj][2]+bj) | ((u32)f2bf(acc[i][jj][3]+bj) << 16);
        *(uint2*)dst = pk;
      }
    }
  }
}

// ------- causal flash attention: batched 64-wide tiles + COUNTED vmcnt -------
// grid 1024 x 256 thr: blk -> (xcd, bh, qt), per-CU balanced qt sets; 4 blocks/CU.
// K-loop now mirrors the GEMM's proven schedule: STAGE(t+1) at top, wait
// vmcnt(4) (tile t, issued one full iteration ago), raw barrier, compute,
// trailing barrier (WAR-safe). No vmcnt(0) drain in steady state.
__global__ __launch_bounds__(256, 4)
void k_attn(const u16* __restrict__ qkv, const u16* __restrict__ vt, u16* __restrict__ yb){
  __shared__ __align__(16) u16 Ks[2][64*64];
  __shared__ __align__(16) u16 Vs[2][64*64];
  int tid = threadIdx.x, wave = tid >> 6, lane = tid & 63;
  int ql = lane & 31, hi = lane >> 5;
  int blk = blockIdx.x;
  int xcd = blk & 7, rest = blk >> 3;
  int bh  = xcd + 8*(rest & 7);
  int qtsel = rest >> 3;
  int a_ = qtsel & 3, g_ = qtsel >> 2;
  int qt = (g_==0) ? (15 - a_) : (g_==1) ? (7 - a_) : (g_==2) ? (8 + a_) : a_;
  int b = bh >> 4, h = bh & 15;

  const u16* Kbase = qkv + (size_t)b*Tn*N1n + Cn + h*HSn;
  const u16* Vbase = vt  + (size_t)bh*HSn*Tn;

  auto STAGE = [&](int bufi, int kt){
    int kb_ = kt*64;
    #pragma unroll
    for (int it=0; it<2; ++it){
      int off = it*4096 + tid*16;
      int row = off >> 7;
      int cb  = off & 127;
      int gc  = (cb ^ ((row & 7) << 4)) >> 1;
      gload_lds16(Kbase + (size_t)(kb_ + row)*N1n + gc,
                  (char*)&Ks[bufi][0] + it*4096 + (wave << 10));
      gload_lds16(Vbase + (size_t)row*Tn + kb_ + gc,
                  (char*)&Vs[bufi][0] + it*4096 + (wave << 10));
    }
  };

  int q0 = qt * 128;
  int qw0 = q0 + wave*32;
  int qg  = qw0 + ql;
  int ntiles = 2*qt + 2;

  // Q B-frags: pre-scaled by QSC in the QKV GEMM epilogue
  const u16* Qp = qkv + (size_t)(b*Tn + qg)*N1n + h*HSn;
  short8 qf[4];
  #pragma unroll
  for (int dc=0; dc<4; ++dc) qf[dc] = *(const short8*)&Qp[dc*16 + hi*8];

  f32x16 accO[2];
  #pragma unroll
  for (int f=0; f<2; ++f)
    #pragma unroll
    for (int r=0; r<16; ++r) accO[f][r] = 0.f;
  float m_ = -1e30f, l_ = 0.f;

  int xsw = (ql & 7) << 4;

  // pack 8 P-values (f32) starting at sX[pb] into one B-frag and do 2 PV MFMAs
  auto PVS = [&](const f32x16& sx, int pb, int voff, const char* Vsb){
    u32 w0 = pkbf(sx[pb+0], sx[pb+1]);
    u32 w1 = pkbf(sx[pb+2], sx[pb+3]);
    u32 w2 = pkbf(sx[pb+4], sx[pb+5]);
    u32 w3 = pkbf(sx[pb+6], sx[pb+7]);
    plswap(w0, w2);
    plswap(w1, w3);
    union { u32 w[4]; short8 v; } pu;
    pu.w[0] = w0; pu.w[1] = w1; pu.w[2] = w2; pu.w[3] = w3;
    __builtin_amdgcn_s_setprio(1);
    #pragma unroll
    for (int f=0; f<2; ++f){
      short8 vf = *(const short8*)(Vsb + ((f*32 + ql) << 7) + ((voff + hi*16) ^ xsw));
      accO[f] = __builtin_amdgcn_mfma_f32_32x32x16_bf16(vf, pu.v, accO[f], 0, 0, 0);
    }
    __builtin_amdgcn_s_setprio(0);
  };

  STAGE(0, 0);                    // 4 loads in flight (tile 0)
  int buf = 0;

  for (int kt=0; kt<ntiles; ++kt){
    if (kt+1 < ntiles){
      STAGE(buf^1, kt+1);         // +4 -> 8 in flight
      asm volatile("s_waitcnt vmcnt(4)" ::: "memory");  // my tile-kt loads landed
    } else {
      asm volatile("s_waitcnt vmcnt(0)" ::: "memory");
    }
    BARRIER(); CFENCE();          // all waves' tile-kt parts landed
    const char* Ksb = (const char*)&Ks[buf][0];
    const char* Vsb = (const char*)&Vs[buf][0];
    if (kt*64 + 63 <= qw0){
      // ---------- fast path: full 64-wide tile, fused softmax ----------
      f32x16 s0, s1;
      #pragma unroll
      for (int r=0; r<16; ++r){ s0[r]=0.f; s1[r]=0.f; }
      __builtin_amdgcn_s_setprio(1);
      #pragma unroll
      for (int dc=0; dc<4; ++dc){
        short8 kf0 = *(const short8*)(Ksb + ((     ql) << 7) + ((dc*32 + hi*16) ^ xsw));
        short8 kf1 = *(const short8*)(Ksb + ((32 + ql) << 7) + ((dc*32 + hi*16) ^ xsw));
        s0 = __builtin_amdgcn_mfma_f32_32x32x16_bf16(kf0, qf[dc], s0, 0, 0, 0);
        s1 = __builtin_amdgcn_mfma_f32_32x32x16_bf16(kf1, qf[dc], s1, 0, 0, 0);
      }
      __builtin_amdgcn_s_setprio(0);
      float a0 = fmax3(s0[0], s0[1], s0[2]);
      float a1 = fmax3(s0[3], s0[4], s0[5]);
      float a2 = fmax3(s0[6], s0[7], s0[8]);
      float a3 = fmax3(s0[9], s0[10], s0[11]);
      float a4 = fmax3(s0[12], s0[13], s0[14]);
      float ta = fmaxf(fmax3(a0, a1, a2), fmax3(a3, a4, s0[15]));
      float b0 = fmax3(s1[0], s1[1], s1[2]);
      float b1 = fmax3(s1[3], s1[4], s1[5]);
      float b2 = fmax3(s1[6], s1[7], s1[8]);
      float b3 = fmax3(s1[9], s1[10], s1[11]);
      float b4 = fmax3(s1[12], s1[13], s1[14]);
      float tb = fmaxf(fmax3(b0, b1, b2), fmax3(b3, b4, s1[15]));
      float tm = fmaxf(ta, tb);
      { u32 ua = __float_as_uint(tm), ub = ua; plswap(ua, ub);
        tm = fmaxf(__uint_as_float(ua), __uint_as_float(ub)); }
      if (!__all(tm - m_ <= 8.0f)){
        float mn = fmaxf(m_, tm);
        float al = fexp2(m_ - mn);
        m_ = mn; l_ *= al;
        #pragma unroll
        for (int f=0; f<2; ++f)
          #pragma unroll
          for (int r=0; r<16; ++r) accO[f][r] *= al;
      }
      float ls = 0.f;
      #pragma unroll
      for (int r=0; r<16; ++r){ float e = fexp2(s0[r] - m_); s0[r] = e; ls += e; }
      #pragma unroll
      for (int r=0; r<16; ++r){ float e = fexp2(s1[r] - m_); s1[r] = e; ls += e; }
      { u32 ua = __float_as_uint(ls), ub = ua; plswap(ua, ub);
        l_ += __uint_as_float(ua) + __uint_as_float(ub); }
      PVS(s0, 0,  0, Vsb);
      PVS(s0, 8, 32, Vsb);
      PVS(s1, 0, 64, Vsb);
      PVS(s1, 8, 96, Vsb);
    } else {
      // ---------- diagonal tile: per-ksub guarded path ----------
      #pragma unroll
      for (int ksub=0; ksub<2; ++ksub){
        int kbase = kt*64 + ksub*32;
        if (kbase <= qw0 + 31){
          f32x16 s;
          #pragma unroll
          for (int r=0; r<16; ++r) s[r] = 0.f;
          __builtin_amdgcn_s_setprio(1);
          #pragma unroll
          for (int dc=0; dc<4; ++dc){
            short8 kf = *(const short8*)(Ksb + ((ksub*32 + ql) << 7)
                            + ((dc*32 + hi*16) ^ xsw));
            s = __builtin_amdgcn_mfma_f32_32x32x16_bf16(kf, qf[dc], s, 0, 0, 0);
          }
          __builtin_amdgcn_s_setprio(0);
          if (kbase + 31 > qw0){
            #pragma unroll
            for (int r=0; r<16; ++r){
              int krow = kbase + (r&3) + 8*(r>>2) + 4*hi;
              s[r] = (krow > qg) ? -1e30f : s[r];
            }
          }
          float r0 = fmax3(s[0], s[1], s[2]);
          float r1 = fmax3(s[3], s[4], s[5]);
          float r2 = fmax3(s[6], s[7], s[8]);
          float r3 = fmax3(s[9], s[10], s[11]);
          float r4 = fmax3(s[12], s[13], s[14]);
          float tm = fmaxf(fmax3(r0, r1, r2), fmax3(r3, r4, s[15]));
          { u32 ua = __float_as_uint(tm), ub = ua; plswap(ua, ub);
            tm = fmaxf(__uint_as_float(ua), __uint_as_float(ub)); }
          if (!__all(tm - m_ <= 8.0f)){
            float mn = fmaxf(m_, tm);
            float al = fexp2(m_ - mn);
            m_ = mn; l_ *= al;
            #pragma unroll
            for (int f=0; f<2; ++f)
              #pragma unroll
              for (int r=0; r<16; ++r) accO[f][r] *= al;
          }
          float ls = 0.f;
          #pragma unroll
          for (int r=0; r<16; ++r){ float e = fexp2(s[r] - m_); s[r] = e; ls += e; }
          { u32 ua = __float_as_uint(ls), ub = ua; plswap(ua, ub);
            l_ += __uint_as_float(ua) + __uint_as_float(ub); }
          PVS(s, 0, ksub*64,      Vsb);
          PVS(s, 8, ksub*64 + 32, Vsb);
        }
      }
    }
    CFENCE(); BARRIER();          // all waves done reading buf -> next STAGE may overwrite
    buf ^= 1;
  }

  float rl = 1.0f / l_;
  u16* yp = yb + (size_t)(b*Tn + qg)*Cn + h*HSn;
  #pragma unroll
  for (int f=0; f<2; ++f)
    #pragma unroll
    for (int rq=0; rq<4; ++rq){
      int d0 = f*32 + rq*8 + hi*4;
      float v0 = accO[f][rq*4+0]*rl, v1 = accO[f][rq*4+1]*rl;
      float v2 = accO[f][rq*4+2]*rl, v3 = accO[f][rq*4+3]*rl;
      uint2 pk2;
      pk2.x = (u32)f2bf(v0) | ((u32)f2bf(v1) << 16);
      pk2.y = (u32)f2bf(v2) | ((u32)f2bf(v3) << 16);
      *(uint2*)&yp[d0] = pk2;
    }
}

extern "C" void kernel_launch(void* const* d_in, const int* in_sizes, int n_in,
                              void* d_out, int out_size, void* d_ws, size_t ws_size,
                              hipStream_t stream)
{
  const float* x      = (const float*)d_in[0];
  const float* w_attn = (const float*)d_in[1];
  const float* b_attn = (const float*)d_in[2];
  const float* w_proj = (const float*)d_in[3];
  const float* b_proj = (const float*)d_in[4];
  float* out = (float*)d_out;
  char* ws = (char*)d_ws;

  size_t off = 0;
  u16* xb  = (u16*)(ws + off); off += (size_t)Mn*Cn*2;
  u16* waT = (u16*)(ws + off); off += (size_t)N1n*Cn*2;
  u16* wpT = (u16*)(ws + off); off += (size_t)Cn*Cn*2;
  u16* qkv = (u16*)(ws + off); off += (size_t)Mn*N1n*2;
  u16* vt  = (u16*)(ws + off); off += (size_t)Bn*Hn*HSn*Tn*2;
  u16* yb  = (u16*)(ws + off); off += (size_t)Mn*Cn*2;

  (void)hipFuncSetAttribute((const void*)k_gemm2<1>,
        hipFuncAttributeMaxDynamicSharedMemorySize, 65536);
  (void)hipFuncSetAttribute((const void*)k_gemm2<0>,
        hipFuncAttributeMaxDynamicSharedMemorySize, 65536);

  k_pre<<<dim3(5120), 256, 0, stream>>>(x, w_attn, w_proj, xb, waT, wpT);
  k_gemm2<1><<<dim3((Mn/128)*(N1n/128)), 256, 65536, stream>>>(xb, waT, b_attn, qkv, vt, N1n, 8);
  k_attn<<<dim3(1024), 256, 0, stream>>>(qkv, vt, yb);
  k_gemm2<0><<<dim3((Mn/128)*(Cn/128)), 256, 65536, stream>>>(yb, wpT, b_proj, out, nullptr, Cn, 8);
}